// Round 6
// baseline (832.794 us; speedup 1.0000x reference)
//
#include <hip/hip_runtime.h>
#include <hip/hip_bf16.h>

#define T_TOK 4096
#define HDIM  1024
#define FDIM  4096
#define NEXP  8
#define CAP   4096
#define NTMAX 64                  // 256-row tiles: sum ceil(M_e/256) <= 40
#define OBR   8192                // compact rows (sum counts == 8192 exactly)

typedef __attribute__((ext_vector_type(8))) short short8;
typedef __attribute__((ext_vector_type(4))) float floatx4;
typedef __attribute__((ext_vector_type(4))) float float4v;
typedef __attribute__((ext_vector_type(2))) float float2v;
typedef __attribute__((ext_vector_type(4))) unsigned short ushort4v;

__device__ __forceinline__ unsigned short f2bf(float f) {
    union { float f; unsigned int u; } v; v.f = f;
    unsigned int u = v.u;
    u += 0x7fffu + ((u >> 16) & 1u);   // round-to-nearest-even
    return (unsigned short)(u >> 16);
}

__device__ __forceinline__ void gl2lds16(const void* g, void* l) {
    __builtin_amdgcn_global_load_lds(
        (const __attribute__((address_space(1))) unsigned int*)g,
        (__attribute__((address_space(3))) unsigned int*)l,
        16, 0, 0);
}

// ---------------- router (+ x cast): logits, softmax, top-2, lists, per-token slots ----------------
__global__ void k_router(const float* __restrict__ x, const float* __restrict__ wgate,
                         unsigned short* __restrict__ xb,
                         int* __restrict__ counts, int* __restrict__ ltok,
                         float* __restrict__ lwt, int* __restrict__ tslot) {
    int lane = threadIdx.x & 63;
    int tok = blockIdx.x * 4 + (threadIdx.x >> 6);
    const float* xr = x + (size_t)tok * HDIM;
    unsigned short* xbr = xb + (size_t)tok * HDIM;
    float acc[NEXP];
#pragma unroll
    for (int e = 0; e < NEXP; ++e) acc[e] = 0.f;
    for (int it = 0; it < HDIM / 256; ++it) {
        int h0 = it * 256 + lane * 4;
        float4v xv = *(const float4v*)(xr + h0);
        ushort4v xo = { f2bf(xv[0]), f2bf(xv[1]), f2bf(xv[2]), f2bf(xv[3]) };
        *(ushort4v*)(xbr + h0) = xo;
#pragma unroll
        for (int j = 0; j < 4; ++j) {
            float4v w0 = *(const float4v*)(wgate + (size_t)(h0 + j) * NEXP);
            float4v w1 = *(const float4v*)(wgate + (size_t)(h0 + j) * NEXP + 4);
            float xs = xv[j];
            acc[0] += xs * w0[0]; acc[1] += xs * w0[1];
            acc[2] += xs * w0[2]; acc[3] += xs * w0[3];
            acc[4] += xs * w1[0]; acc[5] += xs * w1[1];
            acc[6] += xs * w1[2]; acc[7] += xs * w1[3];
        }
    }
#pragma unroll
    for (int off = 32; off >= 1; off >>= 1)
#pragma unroll
        for (int e = 0; e < NEXP; ++e)
            acc[e] += __shfl_xor(acc[e], off, 64);
    if (lane == 0) {
        float m = acc[0];
#pragma unroll
        for (int e = 1; e < NEXP; ++e) m = fmaxf(m, acc[e]);
        float p[NEXP], s = 0.f;
#pragma unroll
        for (int e = 0; e < NEXP; ++e) { p[e] = __expf(acc[e] - m); s += p[e]; }
        float inv = 1.f / s;
#pragma unroll
        for (int e = 0; e < NEXP; ++e) p[e] *= inv;
        int e0 = 0; float b0 = p[0];
#pragma unroll
        for (int e = 1; e < NEXP; ++e) if (p[e] > b0) { b0 = p[e]; e0 = e; }
        int e1 = -1; float b1 = -1.f;
#pragma unroll
        for (int e = 0; e < NEXP; ++e) if (e != e0 && p[e] > b1) { b1 = p[e]; e1 = e; }
        int p0 = atomicAdd(&counts[e0], 1);
        ltok[e0 * CAP + p0] = tok; lwt[e0 * CAP + p0] = b0;
        int p1 = atomicAdd(&counts[e1], 1);
        ltok[e1 * CAP + p1] = tok; lwt[e1 * CAP + p1] = b1;
        tslot[tok * 2]     = (e0 << 16) | p0;
        tslot[tok * 2 + 1] = (e1 << 16) | p1;
    }
}

// prefix sums + compact (expert, 256-rowtile) worklist. sum ceil(M_e/256) <= 40.
__global__ void k_prefix(const int* __restrict__ counts, int* __restrict__ offs,
                         int* __restrict__ wl, int* __restrict__ nwl) {
    if (threadIdx.x == 0) {
        int s = 0;
#pragma unroll
        for (int e = 0; e < NEXP; ++e) { offs[e] = s; s += counts[e]; }
        int n = 0;
        for (int e = 0; e < NEXP; ++e)
            for (int r = 0; r * 256 < counts[e] && n < NTMAX; ++r)
                wl[n++] = (e << 8) | r;
        nwl[0] = n;
    }
}

// ---------------- GEMM1 v7: h = silu(x@Wg) * (x@Wu) ----------------
// NO transpose pre-pass: B staged directly from fp32 wg/wu with in-register
// transpose+cast (4 coalesced float2 column-pair loads -> f2bf -> 2 ds_write_b64
// into the SAME swizzled [n][k] layout the proven compute() reads).
// A side, compute, epilogue identical to v6. One barrier per K-step; B-loads for
// step k+1 issue before compute(k) (latency hides under MFMA).
__global__ __launch_bounds__(512, 4)
void k_gemm1(const unsigned short* __restrict__ xb,    // [T][H] bf16
             const float* __restrict__ wg,             // [E][H][F] fp32
             const float* __restrict__ wu,             // [E][H][F] fp32
             const int* __restrict__ counts, const int* __restrict__ offs,
             const int* __restrict__ ltok,
             const int* __restrict__ wl, const int* __restrict__ nwl,
             unsigned short* __restrict__ hbuf)        // [OBR][F] bf16
{
    const int bid = blockIdx.x;
    const int ftile = bid & 63;       // consecutive bids share the A-panel
    const int by = bid >> 6;
    if (by >= nwl[0]) return;
    const int w = wl[by];
    const int e = w >> 8, rowtile = w & 255;
    const int M = counts[e];

    __shared__ __align__(16) unsigned short lA[2][256 * 32];   // 2 x 16 KB
    __shared__ __align__(16) unsigned short lBg[2][64 * 32];   // 2 x 4 KB
    __shared__ __align__(16) unsigned short lBu[2][64 * 32];   // 2 x 4 KB
    __shared__ int stok[256];

    const int t = threadIdx.x;
    const int wv = t >> 6, lane = t & 63;

    if (t < 256) {
        int i = rowtile * 256 + t;
        stok[t] = (i < M) ? ltok[e * CAP + i] : ltok[e * CAP];
    }
    __syncthreads();

    // ---- A staging (gl2lds, source-swizzled; unchanged from v6) ----
    const int srow = wv * 16 + (lane >> 2);            // 0..127
    const int k4 = lane & 3;
    const int swA = (k4 ^ ((srow >> 1) & 3)) * 8;
    const unsigned short* pA0 = xb + (size_t)stok[srow] * HDIM + swA;
    const unsigned short* pA1 = xb + (size_t)stok[128 + srow] * HDIM + swA;

    // ---- B staging (fp32 direct, reg transpose+cast) ----
    // waves 0-3: gate, waves 4-7: up. Per thread: 4k x 2n micro-tile.
    const int tt = t & 255;
    const int bn0 = 2 * (tt & 31);                     // 0..62
    const int bk0 = 4 * (tt >> 5);                     // 0..28
    const float* wsrc = (wv < 4) ? wg : wu;
    const float* pB = wsrc + (size_t)e * HDIM * FDIM + (size_t)bk0 * FDIM + ftile * 64 + bn0;
    // LDS element offset in the swizzled [64 n][4 chunk] layout (chunk = 8 k-elems):
    const int wo0 = bn0 * 32 + (((bk0 >> 3) ^ ((bn0 >> 1) & 3)) << 3) + (bk0 & 7);
    // bn0 even -> (bn0+1) has same chunk swizzle -> wo1 = wo0 + 32

    const int wm = wv >> 1, wn = wv & 1;
    const int fr = lane & 15, kg = lane >> 4;
    const int cswz = (kg ^ ((fr >> 1) & 3)) * 8;       // swizzled read chunk

    floatx4 accg[4][2], accu[4][2];
#pragma unroll
    for (int mi = 0; mi < 4; ++mi)
#pragma unroll
        for (int ni = 0; ni < 2; ++ni) {
            floatx4 z = {0.f, 0.f, 0.f, 0.f};
            accg[mi][ni] = z; accu[mi][ni] = z;
        }

    float2v q0, q1, q2, q3;
    auto ldB = [&]() {                 // 4 coalesced float2 loads (rows bk0..bk0+3)
        q0 = *(const float2v*)(pB);
        q1 = *(const float2v*)(pB + FDIM);
        q2 = *(const float2v*)(pB + 2 * FDIM);
        q3 = *(const float2v*)(pB + 3 * FDIM);
        pB += 32 * FDIM;
    };
    auto writeB = [&](int b) {         // cast + transposed ds_write into swizzled layout
        unsigned short* base = ((wv < 4) ? &lBg[b][0] : &lBu[b][0]) + wo0;
        ushort4v lo = { f2bf(q0[0]), f2bf(q1[0]), f2bf(q2[0]), f2bf(q3[0]) };
        ushort4v hi = { f2bf(q0[1]), f2bf(q1[1]), f2bf(q2[1]), f2bf(q3[1]) };
        *(ushort4v*)(base) = lo;
        *(ushort4v*)(base + 32) = hi;
    };
    auto stageA = [&](int b) {
        gl2lds16(pA0, &lA[b][wv * 512]);        pA0 += 32;
        gl2lds16(pA1, &lA[b][4096 + wv * 512]); pA1 += 32;
    };
    auto compute = [&](int b) {
        short8 a[4], g[2], u[2];
#pragma unroll
        for (int mi = 0; mi < 4; ++mi)
            a[mi] = *(const short8*)&lA[b][(wm * 64 + mi * 16 + fr) * 32 + cswz];
#pragma unroll
        for (int ni = 0; ni < 2; ++ni) {
            g[ni] = *(const short8*)&lBg[b][(wn * 32 + ni * 16 + fr) * 32 + cswz];
            u[ni] = *(const short8*)&lBu[b][(wn * 32 + ni * 16 + fr) * 32 + cswz];
        }
#pragma unroll
        for (int mi = 0; mi < 4; ++mi)
#pragma unroll
            for (int ni = 0; ni < 2; ++ni) {
                accg[mi][ni] = __builtin_amdgcn_mfma_f32_16x16x32_bf16(a[mi], g[ni], accg[mi][ni], 0, 0, 0);
                accu[mi][ni] = __builtin_amdgcn_mfma_f32_16x16x32_bf16(a[mi], u[ni], accu[mi][ni], 0, 0, 0);
            }
    };

    // prologue: stage K-step 0
    ldB();
    stageA(0);
    writeB(0);        // compiler inserts the vmcnt wait for q-deps
    __syncthreads();

    // 32 K-steps of BK=32, double-buffered; next-step loads issue before compute
#pragma unroll 1
    for (int it = 0; it < 32; ++it) {
        const int b = it & 1;
        if (it < 31) { ldB(); stageA(b ^ 1); }
        compute(b);
        if (it < 31) writeB(b ^ 1);
        __syncthreads();
    }

    const int hrow0 = offs[e] + rowtile * 256;
#pragma unroll
    for (int mi = 0; mi < 4; ++mi)
#pragma unroll
        for (int ni = 0; ni < 2; ++ni) {
            int c = ftile * 64 + wn * 32 + ni * 16 + fr;
#pragma unroll
            for (int r = 0; r < 4; ++r) {
                int rr = wm * 64 + mi * 16 + kg * 4 + r;
                if (rowtile * 256 + rr < M) {
                    float g = accg[mi][ni][r];
                    float val = (g / (1.f + __expf(-g))) * accu[mi][ni][r];
                    hbuf[(size_t)(hrow0 + rr) * FDIM + c] = f2bf(val);
                }
            }
        }
}

// ---------------- GEMM2 v7: obuf[kq][row] = w * (h @ Wd^T), split-K=4 ----------------
// Same fp32-direct B staging from wd [E][F][H] (K = f): per thread 4k x 2n micro-tile,
// fully-coalesced float2 loads (64 lanes x 8 B = 512 B), cast, 2 ds_write_b64.
__global__ __launch_bounds__(512, 4)
void k_gemm2(const unsigned short* __restrict__ hbuf,  // [OBR][F] bf16
             const float* __restrict__ wd,             // [E][F][H] fp32
             const int* __restrict__ counts, const int* __restrict__ offs,
             const float* __restrict__ lwt,
             const int* __restrict__ wl, const int* __restrict__ nwl,
             float* __restrict__ obuf)                 // [4][OBR][H] fp32
{
    const int bid = blockIdx.x;
    const int htile = bid & 7;        // 0..7
    const int kq = (bid >> 3) & 3;    // 0..3
    const int by = bid >> 5;
    if (by >= nwl[0]) return;
    const int w = wl[by];
    const int e = w >> 8, rowtile = w & 255;
    const int M = counts[e];

    __shared__ __align__(16) unsigned short lA[2][256 * 32];   // 2 x 16 KB
    __shared__ __align__(16) unsigned short lB[2][128 * 32];   // 2 x 8 KB
    __shared__ float swt[256];

    const int t = threadIdx.x;
    const int wv = t >> 6, lane = t & 63;

    if (t < 256) {
        int i = rowtile * 256 + t;
        swt[t] = (i < M) ? lwt[e * CAP + i] : 0.f;
    }

    const int row0 = offs[e] + rowtile * 256;

    // ---- A staging (gl2lds from hbuf; unchanged from v6) ----
    const int srow = wv * 16 + (lane >> 2);            // 0..127
    const int k4 = lane & 3;
    const int swA = (k4 ^ ((srow >> 1) & 3)) * 8;
    const int kofs = kq * (FDIM / 4);
    const int ra0 = min(row0 + srow, OBR - 1);
    const int ra1 = min(row0 + 128 + srow, OBR - 1);
    const unsigned short* pA0 = hbuf + (size_t)ra0 * FDIM + kofs + swA;
    const unsigned short* pA1 = hbuf + (size_t)ra1 * FDIM + kofs + swA;

    // ---- B staging (fp32 direct from wd) ----
    const int bn0 = 2 * (t & 63);                      // 0..126
    const int bk0 = 4 * wv;                            // 0..28
    const float* pB = wd + (size_t)e * FDIM * HDIM + (size_t)(kofs + bk0) * HDIM + htile * 128 + bn0;
    const int wo0 = bn0 * 32 + (((bk0 >> 3) ^ ((bn0 >> 1) & 3)) << 3) + (bk0 & 7);

    const int wm = wv >> 1, wn = wv & 1;
    const int fr = lane & 15, kg = lane >> 4;
    const int cswz = (kg ^ ((fr >> 1) & 3)) * 8;

    floatx4 acc[4][4];
#pragma unroll
    for (int mi = 0; mi < 4; ++mi)
#pragma unroll
        for (int ni = 0; ni < 4; ++ni) {
            floatx4 z = {0.f, 0.f, 0.f, 0.f};
            acc[mi][ni] = z;
        }

    float2v q0, q1, q2, q3;
    auto ldB = [&]() {
        q0 = *(const float2v*)(pB);
        q1 = *(const float2v*)(pB + HDIM);
        q2 = *(const float2v*)(pB + 2 * HDIM);
        q3 = *(const float2v*)(pB + 3 * HDIM);
        pB += 32 * HDIM;
    };
    auto writeB = [&](int b) {
        unsigned short* base = &lB[b][0] + wo0;
        ushort4v lo = { f2bf(q0[0]), f2bf(q1[0]), f2bf(q2[0]), f2bf(q3[0]) };
        ushort4v hi = { f2bf(q0[1]), f2bf(q1[1]), f2bf(q2[1]), f2bf(q3[1]) };
        *(ushort4v*)(base) = lo;
        *(ushort4v*)(base + 32) = hi;
    };
    auto stageA = [&](int b) {
        gl2lds16(pA0, &lA[b][wv * 512]);        pA0 += 32;
        gl2lds16(pA1, &lA[b][4096 + wv * 512]); pA1 += 32;
    };
    auto compute = [&](int b) {
        short8 a[4], bb[4];
#pragma unroll
        for (int mi = 0; mi < 4; ++mi)
            a[mi] = *(const short8*)&lA[b][(wm * 64 + mi * 16 + fr) * 32 + cswz];
#pragma unroll
        for (int ni = 0; ni < 4; ++ni)
            bb[ni] = *(const short8*)&lB[b][(wn * 64 + ni * 16 + fr) * 32 + cswz];
#pragma unroll
        for (int mi = 0; mi < 4; ++mi)
#pragma unroll
            for (int ni = 0; ni < 4; ++ni)
                acc[mi][ni] = __builtin_amdgcn_mfma_f32_16x16x32_bf16(a[mi], bb[ni], acc[mi][ni], 0, 0, 0);
    };

    ldB();
    stageA(0);
    writeB(0);
    __syncthreads();

    // 32 K-steps of BK=32 over this K-quarter
#pragma unroll 1
    for (int it = 0; it < 32; ++it) {
        const int b = it & 1;
        if (it < 31) { ldB(); stageA(b ^ 1); }
        compute(b);
        if (it < 31) writeB(b ^ 1);
        __syncthreads();
    }

    float* ob = obuf + (size_t)kq * OBR * HDIM;
#pragma unroll
    for (int mi = 0; mi < 4; ++mi)
#pragma unroll
        for (int ni = 0; ni < 4; ++ni) {
            int c = htile * 128 + wn * 64 + ni * 16 + fr;
#pragma unroll
            for (int r = 0; r < 4; ++r) {
                int rr = wm * 64 + mi * 16 + kg * 4 + r;
                if (rowtile * 256 + rr < M)
                    ob[(size_t)(row0 + rr) * HDIM + c] = acc[mi][ni][r] * swt[rr];
            }
        }
}

// ---------------- combine: out[tok] = sum over 2 slots x 4 k-quarters ----------------
__global__ void k_combine(const float* __restrict__ obuf, const int* __restrict__ tslot,
                          const int* __restrict__ offs, float* __restrict__ out) {
    int gid = blockIdx.x * 256 + threadIdx.x;
    int tok = gid >> 8;           // 256 threads per token
    int c = (gid & 255) * 4;
    int s0 = tslot[tok * 2], s1 = tslot[tok * 2 + 1];
    size_t r0 = (size_t)(offs[s0 >> 16] + (s0 & 0xFFFF));
    size_t r1 = (size_t)(offs[s1 >> 16] + (s1 & 0xFFFF));
    float4v s = {0.f, 0.f, 0.f, 0.f};
#pragma unroll
    for (int q = 0; q < 4; ++q) {
        s += *(const float4v*)(obuf + ((size_t)q * OBR + r0) * HDIM + c);
        s += *(const float4v*)(obuf + ((size_t)q * OBR + r1) * HDIM + c);
    }
    *(float4v*)(out + (size_t)tok * HDIM + c) = s;
}

extern "C" void kernel_launch(void* const* d_in, const int* in_sizes, int n_in,
                              void* d_out, int out_size, void* d_ws, size_t ws_size,
                              hipStream_t stream) {
    const float* x     = (const float*)d_in[0];  // [4096][1024]
    const float* wgate = (const float*)d_in[1];  // [1024][8]
    const float* wg    = (const float*)d_in[2];  // [8][1024][4096]
    const float* wu    = (const float*)d_in[3];  // [8][1024][4096]
    const float* wd    = (const float*)d_in[4];  // [8][4096][1024]
    float* out = (float*)d_out;

    char* ws = (char*)d_ws;
    size_t off = 0;
    unsigned short* xb  = (unsigned short*)(ws + off); off += (size_t)T_TOK * HDIM * 2;
    unsigned short* hbuf= (unsigned short*)(ws + off); off += (size_t)OBR * FDIM * 2;
    float* obuf = (float*)(ws + off);   off += (size_t)4 * OBR * HDIM * 4;
    int*   ltok   = (int*)(ws + off);   off += (size_t)NEXP * CAP * 4;
    float* lwt    = (float*)(ws + off); off += (size_t)NEXP * CAP * 4;
    int*   tslot  = (int*)(ws + off);   off += (size_t)T_TOK * 2 * 4;
    int*   counts = (int*)(ws + off);   off += 256;
    int*   offs   = (int*)(ws + off);   off += 256;
    int*   wl     = (int*)(ws + off);   off += NTMAX * 4;
    int*   nwl    = (int*)(ws + off);   off += 256;

    hipMemsetAsync(counts, 0, 32, stream);

    k_router<<<T_TOK / 4, 256, 0, stream>>>(x, wgate, xb, counts, ltok, lwt, tslot);
    k_prefix<<<1, 64, 0, stream>>>(counts, offs, wl, nwl);
    k_gemm1<<<64 * 40, 512, 0, stream>>>(xb, wg, wu, counts, offs, ltok, wl, nwl, hbuf);
    k_gemm2<<<32 * 40, 512, 0, stream>>>(hbuf, wd, counts, offs, lwt, wl, nwl, obuf);
    k_combine<<<T_TOK * HDIM / 1024, 256, 0, stream>>>(obuf, tslot, offs, out);
}